// Round 7
// baseline (789.606 us; speedup 1.0000x reference)
//
#include <hip/hip_runtime.h>

typedef unsigned short u16;
typedef unsigned int u32;
typedef __attribute__((ext_vector_type(8))) short short8;
typedef __attribute__((ext_vector_type(4))) float f32x4;

#define DIMC 768
#define NPOS 32768
#define NKT 12   // 768 / 64

__device__ __forceinline__ float b2f(u16 u) {
    union { u32 i; float f; } c; c.i = ((u32)u) << 16; return c.f;
}
__device__ __forceinline__ u16 f2b(float f) {
    union { float f; u32 i; } c; c.f = f;
    u32 r = c.i + 0x7fffu + ((c.i >> 16) & 1u);
    return (u16)(r >> 16);
}

// async global->LDS, 16B per lane; lds dst is wave-uniform base + lane*16
__device__ __forceinline__ void gl_lds16(const void* g, void* l) {
    __builtin_amdgcn_global_load_lds(
        (const __attribute__((address_space(1))) void*)g,
        (__attribute__((address_space(3))) void*)l, 16, 0, 0);
}

// ---- fp32 -> bf16 elementwise (x) ----
__global__ __launch_bounds__(256) void cvt_bf16(
    const float* __restrict__ in, u16* __restrict__ out, int n4)
{
    int i = blockIdx.x * 256 + threadIdx.x;
    if (i >= n4) return;
    float4 v = ((const float4*)in)[i];
    ushort4 o;
    o.x = f2b(v.x); o.y = f2b(v.y); o.z = f2b(v.z); o.w = f2b(v.w);
    ((ushort4*)out)[i] = o;
}

// ---- fp32 W[768][N] -> bf16 WT[N][768] (transpose + convert), 64x64 tiles ----
__global__ __launch_bounds__(256) void cvt_wT(
    const float* __restrict__ W0, const float* __restrict__ W1,
    const float* __restrict__ W2,
    u16* __restrict__ T0, u16* __restrict__ T1, u16* __restrict__ T2)
{
    const int z = blockIdx.z;
    const float* W = (z == 0) ? W0 : (z == 1) ? W1 : W2;
    u16* WT = (z == 0) ? T0 : (z == 1) ? T1 : T2;
    const int N = (z == 2) ? 768 : 2304;
    const int nb = blockIdx.x, kb = blockIdx.y;
    if (nb * 64 >= N) return;                       // block-uniform
    __shared__ u16 T[64][65];
    const int t = threadIdx.x, sr = t >> 2, sc = t & 3;
    {
        const float4* p = (const float4*)(W + (size_t)(kb * 64 + sr) * N + nb * 64 + sc * 16);
        float4 a0 = p[0], a1 = p[1], a2 = p[2], a3 = p[3];
        float vv[16] = {a0.x, a0.y, a0.z, a0.w, a1.x, a1.y, a1.z, a1.w,
                        a2.x, a2.y, a2.z, a2.w, a3.x, a3.y, a3.z, a3.w};
        #pragma unroll
        for (int i = 0; i < 16; ++i)
            T[sc * 16 + i][sr] = f2b(vv[i]);
    }
    __syncthreads();
    {
        u16 vv[16];
        #pragma unroll
        for (int i = 0; i < 16; ++i) vv[i] = T[sr][sc * 16 + i];
        uint4 p0, p1;
        p0.x = vv[0] | ((u32)vv[1] << 16);  p0.y = vv[2] | ((u32)vv[3] << 16);
        p0.z = vv[4] | ((u32)vv[5] << 16);  p0.w = vv[6] | ((u32)vv[7] << 16);
        p1.x = vv[8] | ((u32)vv[9] << 16);  p1.y = vv[10] | ((u32)vv[11] << 16);
        p1.z = vv[12] | ((u32)vv[13] << 16); p1.w = vv[14] | ((u32)vv[15] << 16);
        u16* q = WT + (size_t)(nb * 64 + sr) * DIMC + kb * 64 + sc * 16;
        *(uint4*)q = p0;
        *(uint4*)(q + 8) = p1;
    }
}

// ---- concat biases: [bh(2304) | bw(2304)] -> f32[4608] ----
__global__ __launch_bounds__(256) void biascat(
    const float* __restrict__ bh, const float* __restrict__ bw,
    float* __restrict__ o)
{
    int i = blockIdx.x * 256 + threadIdx.x;
    if (i < 2304) o[i] = bh[i];
    else if (i < 4608) o[i] = bw[i - 2304];
}

// ============================================================================
// 256x256 MFMA GEMM, v7: r3's winning 4-phase/4-barrier rhythm, but
//   (1) B fragments load DIRECT from global (B-panel is L2-resident:
//       merged QKV weights 6.75 MB, per-XCD slice ~384 KB via col-major
//       XCD chunking) -> LDS read traffic/tile drops 24->16 b128 per wave,
//       LDS was the measured critical path (~2000cy/tile vs 620cy MFMA).
//   (2) A triple-buffered in LDS (3 x 32 KB = 96 KB): stages for tile T+2
//       issued at T P3/P4, waited at T+1 P4 via counted vmcnt(4) -> ~5-phase
//       (~1000cy) issue->wait distance, HBM latency fully covered.
// vmcnt soundness (in-order retirement): at tile T P4, newest 4 VMEM = T+2's
// stages; "<=4 outstanding" => everything older retired => T+1's stages AND
// tile-T b-frag loads complete. Every vmcnt precedes a barrier.
// Region safety: buffer s=(T+2)%3 == (T-1)%3; its last reads (tile T-1 P1/P3)
// were consumed >=2 barriers before the stage at T P3.
// ============================================================================

#define STAGE_A(buf, kt, ht) do {                                              \
    gl_lds16(aS + (size_t)((ht) * 128)      * DIMC + (size_t)(kt) * 64,        \
             &As[buf][(ht) * 8192 +        w * 512]);                          \
    gl_lds16(aS + (size_t)((ht) * 128 + 64) * DIMC + (size_t)(kt) * 64,        \
             &As[buf][(ht) * 8192 + 4096 + w * 512]);                          \
} while (0)

// read A half hm (rows hm*128 + wm*64 + i*16 + lr) into af (XOR-swizzled LDS)
#define READ_A(base, hm) do {                                                  \
    _Pragma("unroll")                                                          \
    for (int i_ = 0; i_ < 4; ++i_) {                                           \
        const int row_ = (hm) * 128 + wm * 64 + i_ * 16 + lr;                  \
        _Pragma("unroll")                                                      \
        for (int ks_ = 0; ks_ < 2; ++ks_)                                      \
            af[i_][ks_] = *(const short8*)((base) + (row_ << 6) +              \
                              (((ks_ * 4 + lq) ^ (row_ & 7)) << 3));           \
    }                                                                          \
} while (0)

// load B half hn (rows nBase + hn*128 + wn*32 + j*16 + lr) direct from global
#define GLOAD_B(dst, kt, hn) do {                                              \
    _Pragma("unroll")                                                          \
    for (int j_ = 0; j_ < 2; ++j_) {                                           \
        const int row_ = nBase + (hn) * 128 + wn * 32 + j_ * 16 + lr;          \
        _Pragma("unroll")                                                      \
        for (int ks_ = 0; ks_ < 2; ++ks_)                                      \
            (dst)[j_][ks_] = *(const short8*)(BT + (size_t)row_ * DIMC +       \
                              (size_t)(kt) * 64 + (ks_ * 4 + lq) * 8);         \
    }                                                                          \
} while (0)

#define MM(hm, hn, bsrc) do {                                                  \
    __builtin_amdgcn_s_setprio(1);                                             \
    _Pragma("unroll")                                                          \
    for (int i_ = 0; i_ < 4; ++i_)                                             \
        _Pragma("unroll")                                                      \
        for (int j_ = 0; j_ < 2; ++j_)                                         \
            _Pragma("unroll")                                                  \
            for (int ks_ = 0; ks_ < 2; ++ks_)                                  \
                acc[(hm) * 4 + i_][(hn) * 2 + j_] =                            \
                    __builtin_amdgcn_mfma_f32_16x16x32_bf16(                   \
                        af[i_][ks_], (bsrc)[j_][ks_],                          \
                        acc[(hm) * 4 + i_][(hn) * 2 + j_], 0, 0, 0);           \
    __builtin_amdgcn_s_setprio(0);                                             \
} while (0)

#define BAR() do {                                                             \
    __builtin_amdgcn_sched_barrier(0);                                         \
    __builtin_amdgcn_s_barrier();                                              \
    __builtin_amdgcn_sched_barrier(0);                                         \
} while (0)

// One K-tile. S34: stage tile kt+2's A halves at P3/P4. VN: vmcnt at P4.
#define KTILE(kt, S34, VN) do {                                                \
    const int p_ = (kt) % 3, s_ = ((kt) + 2) % 3;                              \
    /* ---- P1 ---- */                                                         \
    READ_A(As[p_], 0);                                                         \
    GLOAD_B(b0, kt, 0);                                                        \
    GLOAD_B(b1, kt, 1);                                                        \
    BAR();                                                                     \
    MM(0, 0, b0);                                                              \
    /* ---- P2 ---- */                                                         \
    BAR();                                                                     \
    MM(0, 1, b1);                                                              \
    /* ---- P3 ---- */                                                         \
    READ_A(As[p_], 1);                                                         \
    if (S34) STAGE_A(s_, (kt) + 2, 0);                                         \
    BAR();                                                                     \
    MM(1, 0, b0);                                                              \
    /* ---- P4 ---- */                                                         \
    if (S34) STAGE_A(s_, (kt) + 2, 1);                                         \
    __builtin_amdgcn_sched_barrier(0);                                         \
    asm volatile("s_waitcnt vmcnt(" VN ")" ::: "memory");                      \
    BAR();                                                                     \
    MM(1, 1, b1);                                                              \
} while (0)

__global__ __launch_bounds__(512, 2) void gemm256(
    const u16* __restrict__ A, const u16* __restrict__ BT,
    const float* __restrict__ bias, void* __restrict__ C,
    int ldn, int c_is_f32)
{
    __shared__ __align__(16) u16 As[3][256 * 64];   // 96 KiB, triple-buffered

    const int t = threadIdx.x;
    const int w = t >> 6, l = t & 63;
    const int wm = w >> 2, wn = w & 3;              // 2M x 4N wave grid
    const int lr = l & 15, lq = l >> 4;

    // T1: bijective XCD swizzle, then COLUMN-major block order (consecutive
    // swz share bx -> same B-panel stays hot in the XCD's L2)
    const int gx = (int)gridDim.x, gy = (int)gridDim.y;
    const int nwg = gx * gy;                         // 2304 or 384, % 8 == 0
    const int lin = (int)blockIdx.y * gx + (int)blockIdx.x;
    const int swz = (lin & 7) * (nwg >> 3) + (lin >> 3);
    const int bx = swz / gy, by = swz - bx * gy;
    const int mBase = by * 256, nBase = bx * 256;

    // staging source (pre-swizzled so linear global_load_lds yields
    // LDS[row][c] = global chunk c^(row&7))
    const int srow = t >> 3;                         // 0..63
    const int schk = (t & 7) ^ (srow & 7);           // swizzled 16B chunk
    const u16* aS = A + (size_t)(mBase + srow) * DIMC + schk * 8;

    f32x4 acc[8][4];
    #pragma unroll
    for (int i = 0; i < 8; ++i)
        #pragma unroll
        for (int j = 0; j < 4; ++j)
            acc[i][j] = (f32x4){0.f, 0.f, 0.f, 0.f};

    short8 af[4][2], b0[2][2], b1[2][2];

    // prologue: A(tile0)->buf0, A(tile1)->buf1 (8 gl_lds). vmcnt(4) retires
    // tile0's 4 (oldest), leaves tile1's 4 in flight.
    STAGE_A(0, 0, 0); STAGE_A(0, 0, 1);
    STAGE_A(1, 1, 0); STAGE_A(1, 1, 1);
    __builtin_amdgcn_sched_barrier(0);
    asm volatile("s_waitcnt vmcnt(4)" ::: "memory");
    BAR();

    #pragma unroll 1
    for (int kt = 0; kt < NKT - 2; ++kt) { KTILE(kt, 1, "4"); }
    { KTILE(NKT - 2, 0, "0"); }
    { KTILE(NKT - 1, 0, "0"); }

    // epilogue: C/D layout col=lane&15, row=(lane>>4)*4+reg (m89-verified)
    #pragma unroll
    for (int hn = 0; hn < 2; ++hn)
        #pragma unroll
        for (int j = 0; j < 2; ++j) {
            const int col = nBase + hn * 128 + wn * 32 + j * 16 + lr;
            const float bb = bias[col];
            #pragma unroll
            for (int hm = 0; hm < 2; ++hm)
                #pragma unroll
                for (int i = 0; i < 4; ++i) {
                    const int row = mBase + hm * 128 + wm * 64 + i * 16 + lq * 4;
                    #pragma unroll
                    for (int rg = 0; rg < 4; ++rg) {
                        float v = acc[hm * 4 + i][hn * 2 + j][rg] + bb;
                        size_t idx = (size_t)(row + rg) * ldn + col;
                        if (c_is_f32) ((float*)C)[idx] = v;
                        else          ((u16*)C)[idx]   = f2b(v);
                    }
                }
        }
}

// ============================================================================
// Fused dual head-attention, ZERO LDS / zero barriers. One wave per position.
// qkv row (stride 4608) = [h-branch qkv(2304) | w-branch qkv(2304)].
// QK^T via 2x mfma_16x16x32, frags direct from global; softmax via shfl_xor
// within 16-lane groups; PV via v_readlane (wave-uniform P -> SGPR broadcast)
// + fma. Output: 12 x 128B coalesced u16 row-stores, written once.
// ============================================================================
__device__ __forceinline__ void attn_one(
    short8 qa0, short8 qa1, short8 kb0, short8 kb1,
    const float* v, float* o, int lr)
{
    f32x4 s = (f32x4){0.f, 0.f, 0.f, 0.f};
    s = __builtin_amdgcn_mfma_f32_16x16x32_bf16(qa0, kb0, s, 0, 0, 0);
    s = __builtin_amdgcn_mfma_f32_16x16x32_bf16(qa1, kb1, s, 0, 0, 0);
    float pp[4];
    #pragma unroll
    for (int rg = 0; rg < 4; ++rg) {
        float x = (lr < 12) ? s[rg] * 0.125f : -1e30f;
        float m = x;
        m = fmaxf(m, __shfl_xor(m, 1));
        m = fmaxf(m, __shfl_xor(m, 2));
        m = fmaxf(m, __shfl_xor(m, 4));
        m = fmaxf(m, __shfl_xor(m, 8));
        float e = (lr < 12) ? __expf(x - m) : 0.f;
        float ss = e;
        ss += __shfl_xor(ss, 1);
        ss += __shfl_xor(ss, 2);
        ss += __shfl_xor(ss, 4);
        ss += __shfl_xor(ss, 8);
        pp[rg] = e / ss;
    }
    #pragma unroll
    for (int g = 0; g < 12; ++g) {
        #pragma unroll
        for (int h = 0; h < 12; ++h) {
            union { float f; int i; } cb;
            cb.i = __builtin_amdgcn_readlane(
                __builtin_bit_cast(int, pp[h & 3]), (h >> 2) * 16 + g);
            o[h] = fmaf(cb.f, v[g], o[h]);
        }
    }
}

__global__ __launch_bounds__(256) void headattn2(
    const u16* __restrict__ qkv, u16* __restrict__ sum)
{
    const int t = threadIdx.x, wv = t >> 6, l = t & 63;
    const int p = blockIdx.x * 4 + wv;
    const u16* r1 = qkv + (size_t)p * 4608;
    const u16* r2 = r1 + 2304;
    const int lr = l & 15;
    const int fo = lr * 64 + (l >> 4) * 8;          // frag offset

    short8 qa0_1 = *(const short8*)(r1 + fo);
    short8 qa1_1 = *(const short8*)(r1 + fo + 32);
    short8 kb0_1 = *(const short8*)(r1 + 768 + fo);
    short8 kb1_1 = *(const short8*)(r1 + 768 + fo + 32);
    short8 qa0_2 = *(const short8*)(r2 + fo);
    short8 qa1_2 = *(const short8*)(r2 + fo + 32);
    short8 kb0_2 = *(const short8*)(r2 + 768 + fo);
    short8 kb1_2 = *(const short8*)(r2 + 768 + fo + 32);
    float v1[12], v2[12];
    #pragma unroll
    for (int g = 0; g < 12; ++g) {
        v1[g] = b2f(r1[1536 + g * 64 + l]);   // 128B coalesced per g
        v2[g] = b2f(r2[1536 + g * 64 + l]);
    }

    float o[12];
    #pragma unroll
    for (int h = 0; h < 12; ++h) o[h] = 0.f;

    attn_one(qa0_1, qa1_1, kb0_1, kb1_1, v1, o, lr);
    attn_one(qa0_2, qa1_2, kb0_2, kb1_2, v2, o, lr);

    u16* orow = sum + (size_t)p * DIMC;
    #pragma unroll
    for (int h = 0; h < 12; ++h)
        orow[h * 64 + l] = f2b(o[h]);         // 128B coalesced per h
}

extern "C" void kernel_launch(void* const* d_in, const int* in_sizes, int n_in,
                              void* d_out, int out_size, void* d_ws, size_t ws_size,
                              hipStream_t stream) {
    const float* x  = (const float*)d_in[0];
    const float* wh = (const float*)d_in[1];
    const float* bh = (const float*)d_in[2];
    const float* ww = (const float*)d_in[3];
    const float* bw = (const float*)d_in[4];
    const float* wp = (const float*)d_in[5];
    const float* bp = (const float*)d_in[6];
    float* out = (float*)d_out;

    // ws (u16 elems): xb 25165824 (reused as sumb after QKV GEMM) |
    //   whT 1769472 | wwT 1769472 (contiguous -> one [4608][768] B) |
    //   wpT 589824 | bcat 9216 (f32[4608]) | qkvc 150994944  => ~361 MB
    u16* xb   = (u16*)d_ws;
    u16* sumb = xb;                       // aliases xb (dead after QKV GEMM)
    u16* whT  = xb   + 25165824;
    u16* wwT  = whT  + 1769472;           // adjacent to whT (rows 2304..4607)
    u16* wpT  = wwT  + 1769472;
    float* bcat = (float*)(wpT + 589824);
    u16* qkvc = wpT + 589824 + 9216;

    cvt_bf16<<<24576, 256, 0, stream>>>(x, xb, 6291456);
    dim3 wg(36, 12, 3);
    cvt_wT<<<wg, 256, 0, stream>>>(wh, ww, wp, whT, wwT, wpT);
    biascat<<<18, 256, 0, stream>>>(bh, bw, bcat);

    dim3 gq(4608 / 256, NPOS / 256);      // (18, 128) -> 2304 blocks, 9 rounds
    dim3 gp(DIMC / 256, NPOS / 256);      // (3, 128)  ->  384 blocks

    gemm256<<<gq, 512, 0, stream>>>(xb, whT, bcat, qkvc, 4608, 0);
    headattn2<<<NPOS / 4, 256, 0, stream>>>(qkvc, sumb);
    gemm256<<<gp, 512, 0, stream>>>(sumb, wpT, bp, out, DIMC, 1);
}